// Round 1
// baseline (271.981 us; speedup 1.0000x reference)
//
#include <hip/hip_runtime.h>

// Problem geometry (fixed by the reference): points (P=8192, L=3072, 2) fp32.
// Per row: 1024 triplets (p1,p2,p3 = strided 3), p4 = roll of p1 by -1.
// Output: scalar mean over 8192*1024 = 2^23 "xing" values.

#define NTHREADS 256
#define NBLOCKS  2048
#define TRIP_PER_ROW 1024           // L/3
#define ITEMS_PER_ROW 512           // each work-item = 2 triplets
#define ROW_FLOATS 6144             // L*2

__device__ __forceinline__ float xing1(float p1x, float p1y, float p2x, float p2y,
                                       float p3x, float p3y, float p4x, float p4y) {
    float v12x = p2x - p1x, v12y = p2y - p1y;
    float v23x = p3x - p2x, v23y = p3y - p2y;
    float v43x = p4x - p3x, v43y = p4y - p3y;
    float c1 = v12x * v23y - v12y * v23x;          // outer(v12, v23)
    float c2 = v12x * v43y - v12y * v43x;          // outer(v12, v43)
    float d12 = v12x * v12x + v12y * v12y;
    float d43 = v43x * v43x + v43y * v43y;
    float D2 = c2 / (sqrtf(d12) * sqrtf(d43));     // match ref: norm(v12)*norm(v43)
    // D1 = (c1 > 0); xing = D1*relu(-D2) + (1-D1)*relu(D2) = relu(c1>0 ? -D2 : D2)
    float s = (c1 > 0.0f) ? -D2 : D2;
    return fmaxf(s, 0.0f);
}

__global__ __launch_bounds__(NTHREADS) void xing_partial(const float* __restrict__ pts,
                                                         float* __restrict__ partial,
                                                         int itemsTotal) {
    float acc = 0.0f;
    for (int w = blockIdx.x * NTHREADS + threadIdx.x; w < itemsTotal;
         w += NBLOCKS * NTHREADS) {
        int row = w >> 9;                 // / ITEMS_PER_ROW
        int t   = w & (ITEMS_PER_ROW - 1);
        const float* base = pts + (size_t)row * ROW_FLOATS + t * 12;

        // 12 contiguous floats: triplets A (p1,p2,p3) and B (p1',p2',p3')
        float4 a = *reinterpret_cast<const float4*>(base);      // p1.x p1.y p2.x p2.y
        float4 b = *reinterpret_cast<const float4*>(base + 4);  // p3.x p3.y p1'.x p1'.y
        float4 c = *reinterpret_cast<const float4*>(base + 8);  // p2'.x p2'.y p3'.x p3'.y

        // p4 of triplet B = p1 of the (t*2+2)-th triplet, with wrap at row end
        int nextOff = (t == ITEMS_PER_ROW - 1) ? 0 : (t * 12 + 12);
        float2 d = *reinterpret_cast<const float2*>(pts + (size_t)row * ROW_FLOATS + nextOff);

        // triplet A: p4 = p1' = (b.z, b.w) — always in-thread, no wrap possible
        acc += xing1(a.x, a.y, a.z, a.w, b.x, b.y, b.z, b.w);
        // triplet B: p4 = (d.x, d.y)
        acc += xing1(b.z, b.w, c.x, c.y, c.z, c.w, d.x, d.y);
    }

    // wave (64-lane) reduce
    for (int off = 32; off > 0; off >>= 1) acc += __shfl_down(acc, off);

    __shared__ float wsum[NTHREADS / 64];
    int lane = threadIdx.x & 63;
    int wid  = threadIdx.x >> 6;
    if (lane == 0) wsum[wid] = acc;
    __syncthreads();
    if (threadIdx.x == 0) {
        float s = 0.0f;
        #pragma unroll
        for (int i = 0; i < NTHREADS / 64; ++i) s += wsum[i];
        partial[blockIdx.x] = s;
    }
}

__global__ __launch_bounds__(NTHREADS) void xing_final(const float* __restrict__ partial,
                                                       float* __restrict__ out,
                                                       int n, float invN) {
    float acc = 0.0f;
    for (int i = threadIdx.x; i < n; i += NTHREADS) acc += partial[i];
    for (int off = 32; off > 0; off >>= 1) acc += __shfl_down(acc, off);

    __shared__ float wsum[NTHREADS / 64];
    int lane = threadIdx.x & 63;
    int wid  = threadIdx.x >> 6;
    if (lane == 0) wsum[wid] = acc;
    __syncthreads();
    if (threadIdx.x == 0) {
        float s = 0.0f;
        #pragma unroll
        for (int i = 0; i < NTHREADS / 64; ++i) s += wsum[i];
        out[0] = s * invN;
    }
}

extern "C" void kernel_launch(void* const* d_in, const int* in_sizes, int n_in,
                              void* d_out, int out_size, void* d_ws, size_t ws_size,
                              hipStream_t stream) {
    const float* pts = (const float*)d_in[0];
    float* out = (float*)d_out;
    float* partial = (float*)d_ws;   // NBLOCKS floats = 8 KB

    int P = in_sizes[0] / ROW_FLOATS;            // 8192
    int itemsTotal = P * ITEMS_PER_ROW;          // 4,194,304
    float invN = 1.0f / (float)((long long)P * TRIP_PER_ROW);  // 1/2^23 exact

    xing_partial<<<NBLOCKS, NTHREADS, 0, stream>>>(pts, partial, itemsTotal);
    xing_final<<<1, NTHREADS, 0, stream>>>(partial, out, NBLOCKS, invN);
}

// Round 3
// 269.402 us; speedup vs baseline: 1.0096x; 1.0096x over previous
//
#include <hip/hip_runtime.h>

// points (P=8192, L=3072, 2) fp32. Per row: 1024 triplets (p1,p2,p3 strided 3),
// p4 = roll(p1, -1). Output: scalar mean over P*1024 = 2^23 xing values.
//
// Each work-item = 4 consecutive triplets = 24 contiguous floats = 6 float4
// loads + one float2 tail (next triplet's p1, wrapping at row end; tail bytes
// are L1/L2 hits since the neighboring lane loads them).

#define NTHREADS 256
#define NBLOCKS  2048
#define ROW_FLOATS 6144             // L*2
#define ITEMS_PER_ROW 256           // 1024 triplets / 4 per item

__device__ __forceinline__ float xing1(float p1x, float p1y, float p2x, float p2y,
                                       float p3x, float p3y, float p4x, float p4y) {
    float v12x = p2x - p1x, v12y = p2y - p1y;
    float v23x = p3x - p2x, v23y = p3y - p2y;
    float v43x = p4x - p3x, v43y = p4y - p3y;
    float c1 = v12x * v23y - v12y * v23x;          // outer(v12, v23)
    float c2 = v12x * v43y - v12y * v43x;          // outer(v12, v43)
    float d12 = v12x * v12x + v12y * v12y;
    float d43 = v43x * v43x + v43y * v43y;
    // ref: D2 = c2 / (sqrt(d12)*sqrt(d43));  xing = relu(c1>0 ? -D2 : D2)
    float inv = __builtin_amdgcn_rsqf(d12 * d43);  // v_rsq_f32, inv > 0
    float s = (c1 > 0.0f) ? -c2 : c2;
    return fmaxf(s * inv, 0.0f);
}

__global__ __launch_bounds__(NTHREADS) void xing_partial(const float* __restrict__ pts,
                                                         float* __restrict__ partial,
                                                         int itemsTotal) {
    float acc = 0.0f;
    for (int w = blockIdx.x * NTHREADS + threadIdx.x; w < itemsTotal;
         w += NBLOCKS * NTHREADS) {
        int row = w >> 8;                 // / ITEMS_PER_ROW
        int t   = w & (ITEMS_PER_ROW - 1);
        const float* base = pts + (size_t)row * ROW_FLOATS + t * 24;

        float4 q0 = *reinterpret_cast<const float4*>(base);       // p1a p2a
        float4 q1 = *reinterpret_cast<const float4*>(base + 4);   // p3a p1b
        float4 q2 = *reinterpret_cast<const float4*>(base + 8);   // p2b p3b
        float4 q3 = *reinterpret_cast<const float4*>(base + 12);  // p1c p2c
        float4 q4 = *reinterpret_cast<const float4*>(base + 16);  // p3c p1d
        float4 q5 = *reinterpret_cast<const float4*>(base + 20);  // p2d p3d

        int nextOff = (t == ITEMS_PER_ROW - 1) ? 0 : (t * 24 + 24);
        float2 tl = *reinterpret_cast<const float2*>(pts + (size_t)row * ROW_FLOATS + nextOff);

        acc += xing1(q0.x, q0.y, q0.z, q0.w, q1.x, q1.y, q1.z, q1.w); // A, p4=p1b
        acc += xing1(q1.z, q1.w, q2.x, q2.y, q2.z, q2.w, q3.x, q3.y); // B, p4=p1c
        acc += xing1(q3.x, q3.y, q3.z, q3.w, q4.x, q4.y, q4.z, q4.w); // C, p4=p1d
        acc += xing1(q4.z, q4.w, q5.x, q5.y, q5.z, q5.w, tl.x, tl.y); // D, p4=next p1
    }

    // 64-lane wave reduce, then cross-wave via LDS
    for (int off = 32; off > 0; off >>= 1) acc += __shfl_down(acc, off);

    __shared__ float wsum[NTHREADS / 64];
    int lane = threadIdx.x & 63;
    int wid  = threadIdx.x >> 6;
    if (lane == 0) wsum[wid] = acc;
    __syncthreads();
    if (threadIdx.x == 0) {
        float s = 0.0f;
        #pragma unroll
        for (int i = 0; i < NTHREADS / 64; ++i) s += wsum[i];
        partial[blockIdx.x] = s;
    }
}

__global__ __launch_bounds__(NTHREADS) void xing_final(const float* __restrict__ partial,
                                                       float* __restrict__ out,
                                                       int n, float invN) {
    float acc = 0.0f;
    for (int i = threadIdx.x; i < n; i += NTHREADS) acc += partial[i];
    for (int off = 32; off > 0; off >>= 1) acc += __shfl_down(acc, off);

    __shared__ float wsum[NTHREADS / 64];
    int lane = threadIdx.x & 63;
    int wid  = threadIdx.x >> 6;
    if (lane == 0) wsum[wid] = acc;
    __syncthreads();
    if (threadIdx.x == 0) {
        float s = 0.0f;
        #pragma unroll
        for (int i = 0; i < NTHREADS / 64; ++i) s += wsum[i];
        out[0] = s * invN;
    }
}

extern "C" void kernel_launch(void* const* d_in, const int* in_sizes, int n_in,
                              void* d_out, int out_size, void* d_ws, size_t ws_size,
                              hipStream_t stream) {
    const float* pts = (const float*)d_in[0];
    float* out = (float*)d_out;
    float* partial = (float*)d_ws;               // NBLOCKS floats = 8 KB

    int P = in_sizes[0] / ROW_FLOATS;            // 8192
    int itemsTotal = P * ITEMS_PER_ROW;          // 2,097,152
    float invN = 1.0f / (float)((long long)P * 1024); // 1/2^23 exact

    xing_partial<<<NBLOCKS, NTHREADS, 0, stream>>>(pts, partial, itemsTotal);
    xing_final<<<1, NTHREADS, 0, stream>>>(partial, out, NBLOCKS, invN);
}